// Round 14
// baseline (504.825 us; speedup 1.0000x reference)
//
#include <hip/hip_runtime.h>
#include <cstdint>

#define BQ 4
#define QPB 65536
#define QTOT (BQ*QPB)          /* 262144 */
#define TRIN 393216            /* 3*32*64*64 */
#define TRI_OUT (BQ*TRIN)      /* 1572864 */

#define ACTLD 528              /* padded act row stride (bytes) */

typedef __attribute__((ext_vector_type(8))) __bf16 bf16x8;
typedef __attribute__((ext_vector_type(4))) float f32x4;

__device__ __forceinline__ unsigned short f2bf(float f) {
    unsigned u = __float_as_uint(f);
    u += 0x7fffu + ((u >> 16) & 1u);
    return (unsigned short)(u >> 16);
}
__device__ __forceinline__ float bflo(unsigned u) {
    return __uint_as_float(u << 16);
}
__device__ __forceinline__ float bfhi(unsigned u) {
    return __uint_as_float(u & 0xffff0000u);
}
__device__ __forceinline__ unsigned cvt_pk_bf16(float lo, float hi) {
    unsigned r;
    asm("v_cvt_pk_bf16_f32 %0, %1, %2" : "=v"(r) : "v"(lo), "v"(hi));
    return r;
}
__device__ __forceinline__ float fast_rcp(float d) {
    float r;
    asm("v_rcp_f32 %0, %1" : "=v"(r) : "v"(d));
    return r;
}
__device__ __forceinline__ float silu_f(float x) {
    return x * fast_rcp(1.0f + __expf(-x));
}
// stored position within a 64-col group -> true column (sigma^-1)
__device__ __forceinline__ int c_true(int p) {
    return (p & ~63) + ((p & 3) * 16 + ((p & 63) >> 2));
}

// ---------------- K0: pack MLP weights (fragment order + sigma K-permute) ----------------
__global__ __launch_bounds__(256) void k_prep_w(
    const float* __restrict__ mw0, const float* __restrict__ mw1, const float* __restrict__ mw2,
    const float* __restrict__ sdf_w, const float* __restrict__ occ_w,
    unsigned short* __restrict__ wt0, unsigned short* __restrict__ wt1,
    unsigned short* __restrict__ wt2, float* __restrict__ sdfp, float* __restrict__ occp)
{
    int idx = blockIdx.x * 256 + threadIdx.x;
    if (idx < 163840) {
        const float* src;
        unsigned short* dst;
        int rel;
        bool perm;
        int kmax;
        if (idx < 32768)       { rel = idx;         src = mw0; dst = wt0; perm = false; kmax = 99;  }
        else if (idx < 98304)  { rel = idx - 32768; src = mw1; dst = wt1; perm = true;  kmax = 256; }
        else                   { rel = idx - 98304; src = mw2; dst = wt2; perm = true;  kmax = 256; }
        int e  = rel & 7;
        int kg = (rel >> 3) & 3;
        int n  = (rel >> 5) & 255;
        int t  = rel >> 13;
        int ks = t * 32 + kg * 8 + e;          // stored k
        int k  = perm ? c_true(ks) : ks;       // source k
        float v = (ks < kmax) ? src[k * 256 + n] : 0.0f;
        dst[rel] = f2bf(v);
    } else if (idx < 164352) {
        int r = idx - 163840;
        int p = r & 255, which = r >> 8;
        float v = (which ? occ_w : sdf_w)[c_true(p)];
        (which ? occp : sdfp)[p] = v;
    }
}

// ---------------- K1: h = silu(z @ w1 + b1), [4][512] f32 ----------------
__global__ __launch_bounds__(256) void k_h(
    const float* __restrict__ z, const float* __restrict__ w1,
    const float* __restrict__ b1, float* __restrict__ hout)
{
    int gid = blockIdx.x * 256 + threadIdx.x;   // 2048 total
    int b = gid >> 9, n = gid & 511;
    float acc = b1[n];
    #pragma unroll 8
    for (int k = 0; k < 256; ++k)
        acc += z[b * 256 + k] * w1[k * 512 + n];
    hout[gid] = silu_f(acc);
}

// ---------------- K2: triplanes = h @ w2 + b2 (unchanged, near HBM floor) ----------------
__global__ __launch_bounds__(256) void k_triplane(
    const float* __restrict__ w2, const float* __restrict__ b2,
    const float* __restrict__ h, float* __restrict__ outTri,
    unsigned short* __restrict__ triT)
{
    __shared__ float hs[2048];
    int t = threadIdx.x;
    ((float4*)hs)[t]       = ((const float4*)h)[t];
    ((float4*)hs)[t + 256] = ((const float4*)h)[t + 256];
    __syncthreads();
    int g = blockIdx.x * 256 + t;            // 196608 threads
    int j = g * 2;
    const float* wj = w2 + j;
    float ax[4] = {0.f, 0.f, 0.f, 0.f}, ay[4] = {0.f, 0.f, 0.f, 0.f};

    for (int k0 = 0; k0 < 512; k0 += 8) {
        float2 wv[8];
        #pragma unroll
        for (int u = 0; u < 8; ++u)
            wv[u] = *(const float2*)(wj + (size_t)(k0 + u) * TRIN);
        float4 hv[4][2];
        #pragma unroll
        for (int b = 0; b < 4; ++b) {
            hv[b][0] = *(const float4*)&hs[b * 512 + k0];
            hv[b][1] = *(const float4*)&hs[b * 512 + k0 + 4];
        }
        #pragma unroll
        for (int b = 0; b < 4; ++b) {
            ax[b] += hv[b][0].x * wv[0].x + hv[b][0].y * wv[1].x
                   + hv[b][0].z * wv[2].x + hv[b][0].w * wv[3].x
                   + hv[b][1].x * wv[4].x + hv[b][1].y * wv[5].x
                   + hv[b][1].z * wv[6].x + hv[b][1].w * wv[7].x;
            ay[b] += hv[b][0].x * wv[0].y + hv[b][0].y * wv[1].y
                   + hv[b][0].z * wv[2].y + hv[b][0].w * wv[3].y
                   + hv[b][1].x * wv[4].y + hv[b][1].y * wv[5].y
                   + hv[b][1].z * wv[6].y + hv[b][1].w * wv[7].y;
        }
    }

    float2 bj = *(const float2*)(b2 + j);
    int x = j & 63, y = (j >> 6) & 63, c = (j >> 12) & 31, p = j >> 17;
    int ttb = ((p * 64 + y) * 64 + x) * 32 + c;
    #pragma unroll
    for (int b = 0; b < 4; ++b) {
        float vX = ax[b] + bj.x, vY = ay[b] + bj.y;
        float2 o; o.x = vX; o.y = vY;
        *(float2*)(outTri + (size_t)b * TRIN + j) = o;
        unsigned short* tb = triT + b * TRIN + ttb;
        tb[0]  = f2bf(vX);
        tb[32] = f2bf(vY);
    }
}

// ---------------- K4: fused sample + 3-layer MLP + heads ----------------
// ROW-AUTONOMOUS WAVES: each wave owns 16 rows end-to-end (all 256 cols,
// 16 col-fragments). Zero cross-wave sync after phase B (same-wave LDS RAW
// ordering is automatic). 2 barriers total. LDS 33.8 KB -> 4 blocks/CU.
template<int K>
__device__ __forceinline__ void mlp_layer_w(
    unsigned char* act,
    const unsigned short* __restrict__ wtp, const float* __restrict__ mb,
    int wid, int lane)
{
    const int l15 = lane & 15;
    const int kg = lane >> 4;
    const unsigned char* abase = act + (wid * 16 + l15) * ACTLD + kg * 16;
    f32x4 acc[16];
    #pragma unroll
    for (int cf = 0; cf < 16; ++cf) {
        f32x4 zv = {0.f, 0.f, 0.f, 0.f};
        acc[cf] = zv;
    }
    #pragma unroll
    for (int t = 0; t < K / 32; ++t) {
        uint4 av = *(const uint4*)(abase + t * 64);
        #pragma unroll
        for (int cg = 0; cg < 4; ++cg) {
            uint4 bv[4];
            #pragma unroll
            for (int c4 = 0; c4 < 4; ++c4) {
                int n = cg * 64 + c4 * 16 + l15;
                bv[c4] = *(const uint4*)(wtp + (((t * 256 + n) * 4 + kg) << 3));
            }
            __builtin_amdgcn_s_setprio(1);
            #pragma unroll
            for (int c4 = 0; c4 < 4; ++c4)
                acc[cg * 4 + c4] = __builtin_amdgcn_mfma_f32_16x16x32_bf16(
                    __builtin_bit_cast(bf16x8, av),
                    __builtin_bit_cast(bf16x8, bv[c4]),
                    acc[cg * 4 + c4], 0, 0, 0);
            __builtin_amdgcn_s_setprio(0);
        }
    }
    // epilogue: bias + silu + sigma-packed b64 stores (wave-local rows)
    // lane's outputs: rows wid*16 + kg*4 + jj, cols cf*16 + l15.
    // sigma store position (group g = cf>>2, q = cf&3): g*64 + l15*4 + q.
    unsigned char* sbase = act + (wid * 16 + kg * 4) * ACTLD + l15 * 8;
    #pragma unroll
    for (int jj = 0; jj < 4; ++jj) {
        #pragma unroll
        for (int g = 0; g < 4; ++g) {
            float v0 = silu_f(acc[g * 4 + 0][jj] + mb[(g * 4 + 0) * 16 + l15]);
            float v1 = silu_f(acc[g * 4 + 1][jj] + mb[(g * 4 + 1) * 16 + l15]);
            float v2 = silu_f(acc[g * 4 + 2][jj] + mb[(g * 4 + 2) * 16 + l15]);
            float v3 = silu_f(acc[g * 4 + 3][jj] + mb[(g * 4 + 3) * 16 + l15]);
            uint2 pk;
            pk.x = cvt_pk_bf16(v0, v1);
            pk.y = cvt_pk_bf16(v2, v3);
            *(uint2*)(sbase + jj * ACTLD + g * 128) = pk;
        }
    }
}

__global__ __launch_bounds__(256) void k_mlp(
    const float* __restrict__ qp, const unsigned short* __restrict__ triT,
    const unsigned short* __restrict__ wt0, const unsigned short* __restrict__ wt1,
    const unsigned short* __restrict__ wt2,
    const float* __restrict__ mb0, const float* __restrict__ mb1, const float* __restrict__ mb2,
    const float* __restrict__ sdfp, const float* __restrict__ sdf_b,
    const float* __restrict__ occp, const float* __restrict__ occ_b,
    float* __restrict__ out)
{
    __shared__ __align__(16) unsigned char act[64 * ACTLD];   // 33792 B
    // X0 lives in the 256 B prefix of each 528 B row.
    // scr overlay: unit u (u<192, 32 B) at act[(u>>3)*ACTLD + 256 + (u&7)*32]
    // (upper halves of rows 0..23; dead after the phase-B barrier).
    #define SCR(u) (act + ((u) >> 3) * ACTLD + 256 + ((u) & 7) * 32)
    const int t = threadIdx.x;

    // batch <-> XCD affinity (bijective: 4096 = 8 XCD * 512)
    const int bid = blockIdx.x;
    const int xcd = bid & 7;
    const int batch = xcd >> 1;
    const int brow = (bid >> 3) + ((xcd & 1) << 9);   // 0..1023
    const int row0 = batch * QPB + brow * 64;

    // ---- phase A: per (q,plane) corner BYTE offsets + weights -> scr ----
    if (t < 192) {
        int plane = t >> 6, q = t & 63;
        int gr = row0 + q;
        float px = qp[3 * gr], py = qp[3 * gr + 1], pz = qp[3 * gr + 2];
        float u = (plane == 2) ? py : px;
        float v = (plane == 0) ? py : pz;
        u = fminf(fmaxf(u, -1.f), 1.f);
        v = fminf(fmaxf(v, -1.f), 1.f);
        float xf = (u + 1.f) * 31.5f;
        float yf = (v + 1.f) * 31.5f;
        float x0f = floorf(xf), y0f = floorf(yf);
        float wx = xf - x0f, wy = yf - y0f;
        int xi = min(max((int)x0f, 0), 63);
        int yi = min(max((int)y0f, 0), 63);
        int xi1 = min(xi + 1, 63), yi1 = min(yi + 1, 63);
        int pb = (batch * 3 + plane) * 64;
        int4 offs;                             // byte offsets (64 B bf16 rows)
        offs.x = ((pb + yi ) * 64 + xi ) << 6;
        offs.y = ((pb + yi ) * 64 + xi1) << 6;
        offs.z = ((pb + yi1) * 64 + xi ) << 6;
        offs.w = ((pb + yi1) * 64 + xi1) << 6;
        float4 w;
        w.x = (1.f - wx) * (1.f - wy); w.y = wx * (1.f - wy);
        w.z = (1.f - wx) * wy;         w.w = wx * wy;
        *(int4*)SCR(t) = offs;
        *(float4*)(SCR(t) + 16) = w;
        if (plane == 0) {
            uint4 c0;
            c0.x = (unsigned)f2bf(px) | ((unsigned)f2bf(py) << 16);
            c0.y = (unsigned)f2bf(pz);
            c0.z = 0u; c0.w = 0u;
            uint4 z4; z4.x = z4.y = z4.z = z4.w = 0u;
            *(uint4*)(act + q * ACTLD + 192) = c0;
            *(uint4*)(act + q * ACTLD + 208) = z4;
            *(uint4*)(act + q * ACTLD + 224) = z4;
            *(uint4*)(act + q * ACTLD + 240) = z4;
        }
    }
    __syncthreads();

    // ---- phase B: gather+blend from bf16 triT; 768 units = 192 x 4 chunks ----
    const char* tb8 = (const char*)triT;
    #pragma unroll
    for (int i = 0; i < 3; ++i) {
        int unit = i * 256 + t;
        int chunk = unit & 3;
        int uc = unit >> 2;                  // = plane*64 + q
        const unsigned char* ce = SCR(uc);
        int4 offs = *(const int4*)ce;
        float4 w = *(const float4*)(ce + 16);
        int cb = chunk * 16;
        uint4 c0 = *(const uint4*)(tb8 + offs.x + cb);
        uint4 c1 = *(const uint4*)(tb8 + offs.y + cb);
        uint4 c2 = *(const uint4*)(tb8 + offs.z + cb);
        uint4 c3 = *(const uint4*)(tb8 + offs.w + cb);
        const unsigned* u0 = (const unsigned*)&c0;
        const unsigned* u1 = (const unsigned*)&c1;
        const unsigned* u2 = (const unsigned*)&c2;
        const unsigned* u3 = (const unsigned*)&c3;
        unsigned r[4];
        #pragma unroll
        for (int q2 = 0; q2 < 4; ++q2) {
            float lo = w.x * bflo(u0[q2]) + w.y * bflo(u1[q2])
                     + w.z * bflo(u2[q2]) + w.w * bflo(u3[q2]);
            float hi = w.x * bfhi(u0[q2]) + w.y * bfhi(u1[q2])
                     + w.z * bfhi(u2[q2]) + w.w * bfhi(u3[q2]);
            r[q2] = cvt_pk_bf16(lo, hi);
        }
        int q = uc & 63, plane = uc >> 6;
        uint4 pk; pk.x = r[0]; pk.y = r[1]; pk.z = r[2]; pk.w = r[3];
        *(uint4*)(act + q * ACTLD + plane * 64 + chunk * 16) = pk;
    }
    __syncthreads();
    // ---- from here: zero barriers; each wave owns rows wid*16..wid*16+15 ----

    const int lane = t & 63;
    const int wid = t >> 6;                  // row-wave 0..3

    mlp_layer_w<128>(act, wt0, mb0, wid, lane);
    mlp_layer_w<256>(act, wt1, mb1, wid, lane);
    mlp_layer_w<256>(act, wt2, mb2, wid, lane);

    // ---- heads: sdf / occ (wave-local rows; sigma-permuted cols + weights) ----
    {
        const int l15 = lane & 15;
        const int kg = lane >> 4;
        int row = wid * 16 + l15;            // 0..63
        int gr = row0 + row;
        const unsigned char* hbase = act + row * ACTLD + kg * 128;
        float aS = 0.f, aO = 0.f;
        int kb = kg * 64;
        #pragma unroll
        for (int i = 0; i < 8; ++i) {
            int k = kb + i * 8;
            uint4 xv = *(const uint4*)(hbase + i * 16);
            const unsigned* xu = (const unsigned*)&xv;
            float4 s0 = *(const float4*)(sdfp + k);
            float4 s1 = *(const float4*)(sdfp + k + 4);
            float4 o0 = *(const float4*)(occp + k);
            float4 o1 = *(const float4*)(occp + k + 4);
            float xr[8];
            #pragma unroll
            for (int q = 0; q < 4; ++q) {
                xr[2 * q]     = bflo(xu[q]);
                xr[2 * q + 1] = bfhi(xu[q]);
            }
            aS += xr[0] * s0.x + xr[1] * s0.y + xr[2] * s0.z + xr[3] * s0.w
                + xr[4] * s1.x + xr[5] * s1.y + xr[6] * s1.z + xr[7] * s1.w;
            aO += xr[0] * o0.x + xr[1] * o0.y + xr[2] * o0.z + xr[3] * o0.w
                + xr[4] * o1.x + xr[5] * o1.y + xr[6] * o1.z + xr[7] * o1.w;
        }
        aS += __shfl_xor(aS, 16);
        aS += __shfl_xor(aS, 32);
        aO += __shfl_xor(aO, 16);
        aO += __shfl_xor(aO, 32);
        if (kg == 0) {
            out[TRI_OUT + gr] = aS + sdf_b[0];
            out[TRI_OUT + QTOT + gr] = aO + occ_b[0];
        }
    }
    #undef SCR
}

extern "C" void kernel_launch(void* const* d_in, const int* in_sizes, int n_in,
                              void* d_out, int out_size, void* d_ws, size_t ws_size,
                              hipStream_t stream)
{
    const float* z     = (const float*)d_in[0];
    const float* qp    = (const float*)d_in[1];
    const float* w1    = (const float*)d_in[2];
    const float* b1    = (const float*)d_in[3];
    const float* w2    = (const float*)d_in[4];
    const float* b2    = (const float*)d_in[5];
    const float* mw0   = (const float*)d_in[6];
    const float* mb0   = (const float*)d_in[7];
    const float* mw1   = (const float*)d_in[8];
    const float* mb1   = (const float*)d_in[9];
    const float* mw2   = (const float*)d_in[10];
    const float* mb2   = (const float*)d_in[11];
    const float* sdf_w = (const float*)d_in[12];
    const float* sdf_b = (const float*)d_in[13];
    const float* occ_w = (const float*)d_in[14];
    const float* occ_b = (const float*)d_in[15];
    float* out = (float*)d_out;
    char* ws = (char*)d_ws;

    float* h_ws          = (float*)(ws);                    // 8192 B
    unsigned short* wt0  = (unsigned short*)(ws + 8192);    // 65536 B
    unsigned short* wt1  = (unsigned short*)(ws + 73728);   // 131072 B
    unsigned short* wt2  = (unsigned short*)(ws + 204800);  // 131072 B
    float* sdfp          = (float*)(ws + 335872);           // 1024 B
    float* occp          = (float*)(ws + 336896);           // 1024 B
    unsigned short* triT = (unsigned short*)(ws + 337920);  // 3145728 B (bf16)

    k_prep_w<<<643, 256, 0, stream>>>(mw0, mw1, mw2, sdf_w, occ_w,
                                      wt0, wt1, wt2, sdfp, occp);
    k_h<<<8, 256, 0, stream>>>(z, w1, b1, h_ws);
    k_triplane<<<768, 256, 0, stream>>>(w2, b2, h_ws, out, triT);
    k_mlp<<<4096, 256, 0, stream>>>(qp, triT, wt0, wt1, wt2,
                                    mb0, mb1, mb2, sdfp, sdf_b, occp, occ_b, out);
}

// Round 15
// 301.324 us; speedup vs baseline: 1.6754x; 1.6754x over previous
//
#include <hip/hip_runtime.h>
#include <cstdint>

#define BQ 4
#define QPB 65536
#define QTOT (BQ*QPB)          /* 262144 */
#define TRIN 393216            /* 3*32*64*64 */
#define TRI_OUT (BQ*TRIN)      /* 1572864 */

#define X0LD 272               /* padded x0 row stride (bytes) */
#define ACTLD 528              /* padded act row stride (bytes) */

typedef __attribute__((ext_vector_type(8))) __bf16 bf16x8;
typedef __attribute__((ext_vector_type(4))) float f32x4;
typedef __attribute__((ext_vector_type(2))) float f32x2;

__device__ __forceinline__ unsigned short f2bf(float f) {
    unsigned u = __float_as_uint(f);
    u += 0x7fffu + ((u >> 16) & 1u);
    return (unsigned short)(u >> 16);
}
__device__ __forceinline__ float bflo(unsigned u) {
    return __uint_as_float(u << 16);
}
__device__ __forceinline__ float bfhi(unsigned u) {
    return __uint_as_float(u & 0xffff0000u);
}
__device__ __forceinline__ f32x2 lohi2(unsigned u) {
    f32x2 r; r[0] = bflo(u); r[1] = bfhi(u); return r;
}
__device__ __forceinline__ f32x2 mk2(float a, float b) {
    f32x2 r; r[0] = a; r[1] = b; return r;
}
__device__ __forceinline__ f32x2 fma2(f32x2 a, f32x2 b, f32x2 c) {
    return __builtin_elementwise_fma(a, b, c);
}
__device__ __forceinline__ unsigned cvt_pk_bf16(float lo, float hi) {
    unsigned r;
    asm("v_cvt_pk_bf16_f32 %0, %1, %2" : "=v"(r) : "v"(lo), "v"(hi));
    return r;
}
__device__ __forceinline__ float fast_rcp(float d) {
    float r;
    asm("v_rcp_f32 %0, %1" : "=v"(r) : "v"(d));
    return r;
}
__device__ __forceinline__ float silu_f(float x) {
    return x * fast_rcp(1.0f + __expf(-x));
}
__device__ __forceinline__ f32x2 silu2(f32x2 x) {
    f32x2 e; e[0] = __expf(-x[0]); e[1] = __expf(-x[1]);
    f32x2 one = {1.f, 1.f};
    f32x2 d = e + one;                       // pk add
    f32x2 r; r[0] = fast_rcp(d[0]); r[1] = fast_rcp(d[1]);
    return x * r;                            // pk mul
}
// stored position within a 64-col group -> true column (sigma^-1)
__device__ __forceinline__ int c_true(int p) {
    return (p & ~63) + ((p & 3) * 16 + ((p & 63) >> 2));
}

// ---------------- K0: pack MLP weights (fragment order + sigma K-permute) ----------------
__global__ __launch_bounds__(256) void k_prep_w(
    const float* __restrict__ mw0, const float* __restrict__ mw1, const float* __restrict__ mw2,
    const float* __restrict__ sdf_w, const float* __restrict__ occ_w,
    unsigned short* __restrict__ wt0, unsigned short* __restrict__ wt1,
    unsigned short* __restrict__ wt2, float* __restrict__ sdfp, float* __restrict__ occp)
{
    int idx = blockIdx.x * 256 + threadIdx.x;
    if (idx < 163840) {
        const float* src;
        unsigned short* dst;
        int rel;
        bool perm;
        int kmax;
        if (idx < 32768)       { rel = idx;         src = mw0; dst = wt0; perm = false; kmax = 99;  }
        else if (idx < 98304)  { rel = idx - 32768; src = mw1; dst = wt1; perm = true;  kmax = 256; }
        else                   { rel = idx - 98304; src = mw2; dst = wt2; perm = true;  kmax = 256; }
        int e  = rel & 7;
        int kg = (rel >> 3) & 3;
        int n  = (rel >> 5) & 255;
        int t  = rel >> 13;
        int ks = t * 32 + kg * 8 + e;          // stored k
        int k  = perm ? c_true(ks) : ks;       // source k
        float v = (ks < kmax) ? src[k * 256 + n] : 0.0f;
        dst[rel] = f2bf(v);
    } else if (idx < 164352) {
        int r = idx - 163840;
        int p = r & 255, which = r >> 8;
        float v = (which ? occ_w : sdf_w)[c_true(p)];
        (which ? occp : sdfp)[p] = v;
    }
}

// ---------------- K1: h = silu(z @ w1 + b1), [4][512] f32 ----------------
__global__ __launch_bounds__(256) void k_h(
    const float* __restrict__ z, const float* __restrict__ w1,
    const float* __restrict__ b1, float* __restrict__ hout)
{
    int gid = blockIdx.x * 256 + threadIdx.x;   // 2048 total
    int b = gid >> 9, n = gid & 511;
    float acc = b1[n];
    #pragma unroll 8
    for (int k = 0; k < 256; ++k)
        acc += z[b * 256 + k] * w1[k * 512 + n];
    hout[gid] = silu_f(acc);
}

// ---------------- K2: triplanes = h @ w2 + b2 (unchanged, near HBM floor) ----------------
__global__ __launch_bounds__(256) void k_triplane(
    const float* __restrict__ w2, const float* __restrict__ b2,
    const float* __restrict__ h, float* __restrict__ outTri,
    unsigned short* __restrict__ triT)
{
    __shared__ float hs[2048];
    int t = threadIdx.x;
    ((float4*)hs)[t]       = ((const float4*)h)[t];
    ((float4*)hs)[t + 256] = ((const float4*)h)[t + 256];
    __syncthreads();
    int g = blockIdx.x * 256 + t;            // 196608 threads
    int j = g * 2;
    const float* wj = w2 + j;
    float ax[4] = {0.f, 0.f, 0.f, 0.f}, ay[4] = {0.f, 0.f, 0.f, 0.f};

    for (int k0 = 0; k0 < 512; k0 += 8) {
        float2 wv[8];
        #pragma unroll
        for (int u = 0; u < 8; ++u)
            wv[u] = *(const float2*)(wj + (size_t)(k0 + u) * TRIN);
        float4 hv[4][2];
        #pragma unroll
        for (int b = 0; b < 4; ++b) {
            hv[b][0] = *(const float4*)&hs[b * 512 + k0];
            hv[b][1] = *(const float4*)&hs[b * 512 + k0 + 4];
        }
        #pragma unroll
        for (int b = 0; b < 4; ++b) {
            ax[b] += hv[b][0].x * wv[0].x + hv[b][0].y * wv[1].x
                   + hv[b][0].z * wv[2].x + hv[b][0].w * wv[3].x
                   + hv[b][1].x * wv[4].x + hv[b][1].y * wv[5].x
                   + hv[b][1].z * wv[6].x + hv[b][1].w * wv[7].x;
            ay[b] += hv[b][0].x * wv[0].y + hv[b][0].y * wv[1].y
                   + hv[b][0].z * wv[2].y + hv[b][0].w * wv[3].y
                   + hv[b][1].x * wv[4].y + hv[b][1].y * wv[5].y
                   + hv[b][1].z * wv[6].y + hv[b][1].w * wv[7].y;
        }
    }

    float2 bj = *(const float2*)(b2 + j);
    int x = j & 63, y = (j >> 6) & 63, c = (j >> 12) & 31, p = j >> 17;
    int ttb = ((p * 64 + y) * 64 + x) * 32 + c;
    #pragma unroll
    for (int b = 0; b < 4; ++b) {
        float vX = ax[b] + bj.x, vY = ay[b] + bj.y;
        float2 o; o.x = vX; o.y = vY;
        *(float2*)(outTri + (size_t)b * TRIN + j) = o;
        unsigned short* tb = triT + b * TRIN + ttb;
        tb[0]  = f2bf(vX);
        tb[32] = f2bf(vY);
    }
}

// ---------------- K4: fused sample + 3-layer MLP + heads (R13 structure + pk-math) ----------------
template<int K, bool INPLACE, int LDIN>
__device__ __forceinline__ void mlp_layer(
    const unsigned char* bin, unsigned char* bout,
    const unsigned short* __restrict__ wtp, const float* __restrict__ mb,
    int lane, int c4)
{
    const int l15 = lane & 15;
    const int kg = lane >> 4;
    const int n0 = c4 * 64;
    const unsigned char* abase = bin + l15 * LDIN + kg * 16;   // + rf*16*LDIN + 64t (imm)
    f32x4 acc[4][4];
    #pragma unroll
    for (int rf = 0; rf < 4; ++rf)
        #pragma unroll
        for (int cf = 0; cf < 4; ++cf) {
            f32x4 zv = {0.f, 0.f, 0.f, 0.f};
            acc[rf][cf] = zv;
        }
    #pragma unroll
    for (int t = 0; t < K / 32; ++t) {
        uint4 av[4], bv[4];
        #pragma unroll
        for (int rf = 0; rf < 4; ++rf)
            av[rf] = *(const uint4*)(abase + rf * 16 * LDIN + t * 64);
        #pragma unroll
        for (int cf = 0; cf < 4; ++cf) {
            int n = n0 + 16 * cf + l15;
            bv[cf] = *(const uint4*)(wtp + (((t * 256 + n) * 4 + kg) << 3));
        }
        __builtin_amdgcn_s_setprio(1);
        #pragma unroll
        for (int rf = 0; rf < 4; ++rf)
            #pragma unroll
            for (int cf = 0; cf < 4; ++cf)
                acc[rf][cf] = __builtin_amdgcn_mfma_f32_16x16x32_bf16(
                    __builtin_bit_cast(bf16x8, av[rf]),
                    __builtin_bit_cast(bf16x8, bv[cf]),
                    acc[rf][cf], 0, 0, 0);
        __builtin_amdgcn_s_setprio(0);
    }
    if (INPLACE) __syncthreads();            // all reads of bin done before overwrite
    float bias[4];
    #pragma unroll
    for (int cf = 0; cf < 4; ++cf) bias[cf] = mb[n0 + 16 * cf + l15];
    unsigned char* sbase = bout + kg * 4 * ACTLD + (n0 + l15 * 4) * 2;
    #pragma unroll
    for (int rf = 0; rf < 4; ++rf) {
        // jj-pair packed silu per column fragment (adjacent acc regs -> free vec)
        f32x2 bA = mk2(bias[0], bias[0]), bB = mk2(bias[1], bias[1]);
        f32x2 bC = mk2(bias[2], bias[2]), bD = mk2(bias[3], bias[3]);
        f32x2 sA0 = silu2(__builtin_shufflevector(acc[rf][0], acc[rf][0], 0, 1) + bA);
        f32x2 sA1 = silu2(__builtin_shufflevector(acc[rf][0], acc[rf][0], 2, 3) + bA);
        f32x2 sB0 = silu2(__builtin_shufflevector(acc[rf][1], acc[rf][1], 0, 1) + bB);
        f32x2 sB1 = silu2(__builtin_shufflevector(acc[rf][1], acc[rf][1], 2, 3) + bB);
        f32x2 sC0 = silu2(__builtin_shufflevector(acc[rf][2], acc[rf][2], 0, 1) + bC);
        f32x2 sC1 = silu2(__builtin_shufflevector(acc[rf][2], acc[rf][2], 2, 3) + bC);
        f32x2 sD0 = silu2(__builtin_shufflevector(acc[rf][3], acc[rf][3], 0, 1) + bD);
        f32x2 sD1 = silu2(__builtin_shufflevector(acc[rf][3], acc[rf][3], 2, 3) + bD);
        uint2 pk;
        pk.x = cvt_pk_bf16(sA0[0], sB0[0]); pk.y = cvt_pk_bf16(sC0[0], sD0[0]);
        *(uint2*)(sbase + (rf * 16 + 0) * ACTLD) = pk;
        pk.x = cvt_pk_bf16(sA0[1], sB0[1]); pk.y = cvt_pk_bf16(sC0[1], sD0[1]);
        *(uint2*)(sbase + (rf * 16 + 1) * ACTLD) = pk;
        pk.x = cvt_pk_bf16(sA1[0], sB1[0]); pk.y = cvt_pk_bf16(sC1[0], sD1[0]);
        *(uint2*)(sbase + (rf * 16 + 2) * ACTLD) = pk;
        pk.x = cvt_pk_bf16(sA1[1], sB1[1]); pk.y = cvt_pk_bf16(sC1[1], sD1[1]);
        *(uint2*)(sbase + (rf * 16 + 3) * ACTLD) = pk;
    }
    __syncthreads();
}

__global__ __launch_bounds__(256) void k_mlp(
    const float* __restrict__ qp, const unsigned short* __restrict__ triT,
    const unsigned short* __restrict__ wt0, const unsigned short* __restrict__ wt1,
    const unsigned short* __restrict__ wt2,
    const float* __restrict__ mb0, const float* __restrict__ mb1, const float* __restrict__ mb2,
    const float* __restrict__ sdfp, const float* __restrict__ sdf_b,
    const float* __restrict__ occp, const float* __restrict__ occ_b,
    float* __restrict__ out)
{
    __shared__ __align__(16) unsigned char lds[64 * X0LD + 64 * ACTLD];  // 51200 B
    unsigned char* x0  = lds;                  // 64 rows x 272 B
    unsigned char* act = lds + 64 * X0LD;      // 64 rows x 528 B
    unsigned char* scr = act;                  // 192*32 B coord scratch (dead after phase B)
    const int t = threadIdx.x;

    // batch <-> XCD affinity (bijective: 4096 = 8 XCD * 512)
    const int bid = blockIdx.x;
    const int xcd = bid & 7;
    const int batch = xcd >> 1;
    const int brow = (bid >> 3) + ((xcd & 1) << 9);   // 0..1023
    const int row0 = batch * QPB + brow * 64;

    // ---- phase A: per (q,plane) corner BYTE offsets + weights -> scr ----
    if (t < 192) {
        int plane = t >> 6, q = t & 63;
        int gr = row0 + q;
        float px = qp[3 * gr], py = qp[3 * gr + 1], pz = qp[3 * gr + 2];
        float u = (plane == 2) ? py : px;
        float v = (plane == 0) ? py : pz;
        u = fminf(fmaxf(u, -1.f), 1.f);
        v = fminf(fmaxf(v, -1.f), 1.f);
        float xf = (u + 1.f) * 31.5f;
        float yf = (v + 1.f) * 31.5f;
        float x0f = floorf(xf), y0f = floorf(yf);
        float wx = xf - x0f, wy = yf - y0f;
        int xi = min(max((int)x0f, 0), 63);
        int yi = min(max((int)y0f, 0), 63);
        int xi1 = min(xi + 1, 63), yi1 = min(yi + 1, 63);
        int pb = (batch * 3 + plane) * 64;
        int4 offs;                             // byte offsets (64 B bf16 rows)
        offs.x = ((pb + yi ) * 64 + xi ) << 6;
        offs.y = ((pb + yi ) * 64 + xi1) << 6;
        offs.z = ((pb + yi1) * 64 + xi ) << 6;
        offs.w = ((pb + yi1) * 64 + xi1) << 6;
        float4 w;
        w.x = (1.f - wx) * (1.f - wy); w.y = wx * (1.f - wy);
        w.z = (1.f - wx) * wy;         w.w = wx * wy;
        *(int4*)(scr + t * 32) = offs;
        *(float4*)(scr + t * 32 + 16) = w;
        if (plane == 0) {
            uint4 c0;
            c0.x = (unsigned)f2bf(px) | ((unsigned)f2bf(py) << 16);
            c0.y = (unsigned)f2bf(pz);
            c0.z = 0u; c0.w = 0u;
            uint4 z4; z4.x = z4.y = z4.z = z4.w = 0u;
            *(uint4*)(x0 + q * X0LD + 192) = c0;
            *(uint4*)(x0 + q * X0LD + 208) = z4;
            *(uint4*)(x0 + q * X0LD + 224) = z4;
            *(uint4*)(x0 + q * X0LD + 240) = z4;
        }
    }
    __syncthreads();

    // ---- phase B: gather+blend from bf16 triT; 768 units = 192 x 4 chunks ----
    const char* tb8 = (const char*)triT;
    #pragma unroll
    for (int i = 0; i < 3; ++i) {
        int unit = i * 256 + t;
        int chunk = unit & 3;
        int uc = unit >> 2;                  // = plane*64 + q
        const unsigned char* ce = scr + uc * 32;
        int4 offs = *(const int4*)ce;
        float4 w = *(const float4*)(ce + 16);
        int cb = chunk * 16;
        uint4 c0 = *(const uint4*)(tb8 + offs.x + cb);
        uint4 c1 = *(const uint4*)(tb8 + offs.y + cb);
        uint4 c2 = *(const uint4*)(tb8 + offs.z + cb);
        uint4 c3 = *(const uint4*)(tb8 + offs.w + cb);
        const unsigned* u0 = (const unsigned*)&c0;
        const unsigned* u1 = (const unsigned*)&c1;
        const unsigned* u2 = (const unsigned*)&c2;
        const unsigned* u3 = (const unsigned*)&c3;
        f32x2 wx2 = mk2(w.x, w.x), wy2 = mk2(w.y, w.y);
        f32x2 wz2 = mk2(w.z, w.z), ww2 = mk2(w.w, w.w);
        unsigned r[4];
        #pragma unroll
        for (int q2 = 0; q2 < 4; ++q2) {
            f32x2 s = wx2 * lohi2(u0[q2]);
            s = fma2(wy2, lohi2(u1[q2]), s);
            s = fma2(wz2, lohi2(u2[q2]), s);
            s = fma2(ww2, lohi2(u3[q2]), s);
            r[q2] = cvt_pk_bf16(s[0], s[1]);
        }
        int q = uc & 63, plane = uc >> 6;
        uint4 pk; pk.x = r[0]; pk.y = r[1]; pk.z = r[2]; pk.w = r[3];
        *(uint4*)(x0 + q * X0LD + plane * 64 + chunk * 16) = pk;
    }
    __syncthreads();

    const int lane = t & 63;
    const int c4 = t >> 6;                   // col-wave 0..3

    mlp_layer<128, false, X0LD >(x0,  act, wt0, mb0, lane, c4);
    mlp_layer<256, true,  ACTLD>(act, act, wt1, mb1, lane, c4);
    mlp_layer<256, true,  ACTLD>(act, act, wt2, mb2, lane, c4);

    // ---- heads: sdf / occ (pk-FMA pairs; sigma-permuted cols + weights) ----
    {
        const int l15 = lane & 15;
        const int kg = lane >> 4;
        int row = c4 * 16 + l15;             // 0..63
        int gr = row0 + row;
        const unsigned char* hbase = act + row * ACTLD + kg * 128;
        f32x2 aS2 = mk2(0.f, 0.f), aO2 = mk2(0.f, 0.f);
        int kb = kg * 64;
        #pragma unroll
        for (int i = 0; i < 8; ++i) {
            int k = kb + i * 8;
            uint4 xv = *(const uint4*)(hbase + i * 16);
            const unsigned* xu = (const unsigned*)&xv;
            float4 s0 = *(const float4*)(sdfp + k);
            float4 s1 = *(const float4*)(sdfp + k + 4);
            float4 o0 = *(const float4*)(occp + k);
            float4 o1 = *(const float4*)(occp + k + 4);
            f32x2 xa = lohi2(xu[0]), xb = lohi2(xu[1]);
            f32x2 xc = lohi2(xu[2]), xd = lohi2(xu[3]);
            aS2 = fma2(xa, mk2(s0.x, s0.y), aS2);
            aS2 = fma2(xb, mk2(s0.z, s0.w), aS2);
            aS2 = fma2(xc, mk2(s1.x, s1.y), aS2);
            aS2 = fma2(xd, mk2(s1.z, s1.w), aS2);
            aO2 = fma2(xa, mk2(o0.x, o0.y), aO2);
            aO2 = fma2(xb, mk2(o0.z, o0.w), aO2);
            aO2 = fma2(xc, mk2(o1.x, o1.y), aO2);
            aO2 = fma2(xd, mk2(o1.z, o1.w), aO2);
        }
        float aS = aS2[0] + aS2[1];
        float aO = aO2[0] + aO2[1];
        aS += __shfl_xor(aS, 16);
        aS += __shfl_xor(aS, 32);
        aO += __shfl_xor(aO, 16);
        aO += __shfl_xor(aO, 32);
        if (kg == 0) {
            out[TRI_OUT + gr] = aS + sdf_b[0];
            out[TRI_OUT + QTOT + gr] = aO + occ_b[0];
        }
    }
}

extern "C" void kernel_launch(void* const* d_in, const int* in_sizes, int n_in,
                              void* d_out, int out_size, void* d_ws, size_t ws_size,
                              hipStream_t stream)
{
    const float* z     = (const float*)d_in[0];
    const float* qp    = (const float*)d_in[1];
    const float* w1    = (const float*)d_in[2];
    const float* b1    = (const float*)d_in[3];
    const float* w2    = (const float*)d_in[4];
    const float* b2    = (const float*)d_in[5];
    const float* mw0   = (const float*)d_in[6];
    const float* mb0   = (const float*)d_in[7];
    const float* mw1   = (const float*)d_in[8];
    const float* mb1   = (const float*)d_in[9];
    const float* mw2   = (const float*)d_in[10];
    const float* mb2   = (const float*)d_in[11];
    const float* sdf_w = (const float*)d_in[12];
    const float* sdf_b = (const float*)d_in[13];
    const float* occ_w = (const float*)d_in[14];
    const float* occ_b = (const float*)d_in[15];
    float* out = (float*)d_out;
    char* ws = (char*)d_ws;

    float* h_ws          = (float*)(ws);                    // 8192 B
    unsigned short* wt0  = (unsigned short*)(ws + 8192);    // 65536 B
    unsigned short* wt1  = (unsigned short*)(ws + 73728);   // 131072 B
    unsigned short* wt2  = (unsigned short*)(ws + 204800);  // 131072 B
    float* sdfp          = (float*)(ws + 335872);           // 1024 B
    float* occp          = (float*)(ws + 336896);           // 1024 B
    unsigned short* triT = (unsigned short*)(ws + 337920);  // 3145728 B (bf16)

    k_prep_w<<<643, 256, 0, stream>>>(mw0, mw1, mw2, sdf_w, occ_w,
                                      wt0, wt1, wt2, sdfp, occp);
    k_h<<<8, 256, 0, stream>>>(z, w1, b1, h_ws);
    k_triplane<<<768, 256, 0, stream>>>(w2, b2, h_ws, out, triT);
    k_mlp<<<4096, 256, 0, stream>>>(qp, triT, wt0, wt1, wt2,
                                    mb0, mb1, mb2, sdfp, sdf_b, occp, occ_b, out);
}

// Round 16
// 296.053 us; speedup vs baseline: 1.7052x; 1.0178x over previous
//
#include <hip/hip_runtime.h>
#include <cstdint>

#define BQ 4
#define QPB 65536
#define QTOT (BQ*QPB)          /* 262144 */
#define TRIN 393216            /* 3*32*64*64 */
#define TRI_OUT (BQ*TRIN)      /* 1572864 */

#define X0LD 272               /* padded x0 row stride (bytes) */
#define ACTLD 528              /* padded act row stride (bytes) */

typedef __attribute__((ext_vector_type(8))) __bf16 bf16x8;
typedef __attribute__((ext_vector_type(4))) float f32x4;
typedef __attribute__((ext_vector_type(2))) float f32x2;

__device__ __forceinline__ unsigned short f2bf(float f) {
    unsigned u = __float_as_uint(f);
    u += 0x7fffu + ((u >> 16) & 1u);
    return (unsigned short)(u >> 16);
}
__device__ __forceinline__ float bflo(unsigned u) {
    return __uint_as_float(u << 16);
}
__device__ __forceinline__ float bfhi(unsigned u) {
    return __uint_as_float(u & 0xffff0000u);
}
__device__ __forceinline__ f32x2 lohi2(unsigned u) {
    f32x2 r; r[0] = bflo(u); r[1] = bfhi(u); return r;
}
__device__ __forceinline__ f32x2 mk2(float a, float b) {
    f32x2 r; r[0] = a; r[1] = b; return r;
}
__device__ __forceinline__ f32x2 fma2(f32x2 a, f32x2 b, f32x2 c) {
    return __builtin_elementwise_fma(a, b, c);
}
__device__ __forceinline__ unsigned cvt_pk_bf16(float lo, float hi) {
    unsigned r;
    asm("v_cvt_pk_bf16_f32 %0, %1, %2" : "=v"(r) : "v"(lo), "v"(hi));
    return r;
}
__device__ __forceinline__ float fast_rcp(float d) {
    float r;
    asm("v_rcp_f32 %0, %1" : "=v"(r) : "v"(d));
    return r;
}
__device__ __forceinline__ float silu_f(float x) {
    return x * fast_rcp(1.0f + __expf(-x));
}
__device__ __forceinline__ f32x2 silu2(f32x2 x) {
    f32x2 e; e[0] = __expf(-x[0]); e[1] = __expf(-x[1]);
    f32x2 one = {1.f, 1.f};
    f32x2 d = e + one;
    f32x2 r; r[0] = fast_rcp(d[0]); r[1] = fast_rcp(d[1]);
    return x * r;
}
// stored position within a 64-col group -> true column (sigma^-1)
__device__ __forceinline__ int c_true(int p) {
    return (p & ~63) + ((p & 3) * 16 + ((p & 63) >> 2));
}

// ---------------- K0: weights pack + sigma + heads + h, one launch ----------------
__global__ __launch_bounds__(256) void k_prep(
    const float* __restrict__ mw0, const float* __restrict__ mw1, const float* __restrict__ mw2,
    const float* __restrict__ sdf_w, const float* __restrict__ occ_w,
    const float* __restrict__ z, const float* __restrict__ w1, const float* __restrict__ b1,
    unsigned short* __restrict__ wt0, unsigned short* __restrict__ wt1,
    unsigned short* __restrict__ wt2, float* __restrict__ sdfp, float* __restrict__ occp,
    float* __restrict__ hout)
{
    int idx = blockIdx.x * 256 + threadIdx.x;
    if (idx < 163840) {
        const float* src;
        unsigned short* dst;
        int rel;
        bool perm;
        int kmax;
        if (idx < 32768)       { rel = idx;         src = mw0; dst = wt0; perm = false; kmax = 99;  }
        else if (idx < 98304)  { rel = idx - 32768; src = mw1; dst = wt1; perm = true;  kmax = 256; }
        else                   { rel = idx - 98304; src = mw2; dst = wt2; perm = true;  kmax = 256; }
        int e  = rel & 7;
        int kg = (rel >> 3) & 3;
        int n  = (rel >> 5) & 255;
        int t  = rel >> 13;
        int ks = t * 32 + kg * 8 + e;          // stored k
        int k  = perm ? c_true(ks) : ks;       // source k
        float v = (ks < kmax) ? src[k * 256 + n] : 0.0f;
        dst[rel] = f2bf(v);
    } else if (idx < 164352) {
        int r = idx - 163840;
        int p = r & 255, which = r >> 8;
        float v = (which ? occ_w : sdf_w)[c_true(p)];
        (which ? occp : sdfp)[p] = v;
    } else if (idx < 166400) {
        int gid = idx - 164352;                // 0..2047
        int b = gid >> 9, n = gid & 511;
        float acc = b1[n];
        #pragma unroll 8
        for (int k = 0; k < 256; ++k)
            acc += z[b * 256 + k] * w1[k * 512 + n];
        hout[gid] = silu_f(acc);
    }
}

// ---------------- K2: triplanes = h @ w2 + b2 (unchanged, near HBM floor) ----------------
__global__ __launch_bounds__(256) void k_triplane(
    const float* __restrict__ w2, const float* __restrict__ b2,
    const float* __restrict__ h, float* __restrict__ outTri,
    unsigned short* __restrict__ triT)
{
    __shared__ float hs[2048];
    int t = threadIdx.x;
    ((float4*)hs)[t]       = ((const float4*)h)[t];
    ((float4*)hs)[t + 256] = ((const float4*)h)[t + 256];
    __syncthreads();
    int g = blockIdx.x * 256 + t;            // 196608 threads
    int j = g * 2;
    const float* wj = w2 + j;
    float ax[4] = {0.f, 0.f, 0.f, 0.f}, ay[4] = {0.f, 0.f, 0.f, 0.f};

    for (int k0 = 0; k0 < 512; k0 += 8) {
        float2 wv[8];
        #pragma unroll
        for (int u = 0; u < 8; ++u)
            wv[u] = *(const float2*)(wj + (size_t)(k0 + u) * TRIN);
        float4 hv[4][2];
        #pragma unroll
        for (int b = 0; b < 4; ++b) {
            hv[b][0] = *(const float4*)&hs[b * 512 + k0];
            hv[b][1] = *(const float4*)&hs[b * 512 + k0 + 4];
        }
        #pragma unroll
        for (int b = 0; b < 4; ++b) {
            ax[b] += hv[b][0].x * wv[0].x + hv[b][0].y * wv[1].x
                   + hv[b][0].z * wv[2].x + hv[b][0].w * wv[3].x
                   + hv[b][1].x * wv[4].x + hv[b][1].y * wv[5].x
                   + hv[b][1].z * wv[6].x + hv[b][1].w * wv[7].x;
            ay[b] += hv[b][0].x * wv[0].y + hv[b][0].y * wv[1].y
                   + hv[b][0].z * wv[2].y + hv[b][0].w * wv[3].y
                   + hv[b][1].x * wv[4].y + hv[b][1].y * wv[5].y
                   + hv[b][1].z * wv[6].y + hv[b][1].w * wv[7].y;
        }
    }

    float2 bj = *(const float2*)(b2 + j);
    int x = j & 63, y = (j >> 6) & 63, c = (j >> 12) & 31, p = j >> 17;
    int ttb = ((p * 64 + y) * 64 + x) * 32 + c;
    #pragma unroll
    for (int b = 0; b < 4; ++b) {
        float vX = ax[b] + bj.x, vY = ay[b] + bj.y;
        float2 o; o.x = vX; o.y = vY;
        *(float2*)(outTri + (size_t)b * TRIN + j) = o;
        unsigned short* tb = triT + b * TRIN + ttb;
        tb[0]  = f2bf(vX);
        tb[32] = f2bf(vY);
    }
}

// ---------------- K4: fused sample + 3-layer MLP + heads ----------------
// R13/R15 structure + explicit 1-deep register double-buffer of A/B fragments:
// kstep t+1's 8 uint4 loads issue BEFORE kstep t's MFMA cluster, hiding the
// ~200cy L2 weight latency under the 16-MFMA cluster + wave overlap.
template<int K, bool INPLACE, int LDIN>
__device__ __forceinline__ void mlp_layer(
    const unsigned char* bin, unsigned char* bout,
    const unsigned short* __restrict__ wtp, const float* __restrict__ mb,
    int lane, int c4)
{
    const int l15 = lane & 15;
    const int kg = lane >> 4;
    const int n0 = c4 * 64;
    const unsigned char* abase = bin + l15 * LDIN + kg * 16;
    const unsigned short* wbase = wtp + (((n0 + l15) * 4 + kg) << 3);
    f32x4 acc[4][4];
    #pragma unroll
    for (int rf = 0; rf < 4; ++rf)
        #pragma unroll
        for (int cf = 0; cf < 4; ++cf) {
            f32x4 zv = {0.f, 0.f, 0.f, 0.f};
            acc[rf][cf] = zv;
        }
    uint4 av[4], bv[4];
    #pragma unroll
    for (int rf = 0; rf < 4; ++rf)
        av[rf] = *(const uint4*)(abase + rf * 16 * LDIN);
    #pragma unroll
    for (int cf = 0; cf < 4; ++cf)
        bv[cf] = *(const uint4*)(wbase + (cf * 16 * 4 << 3));
    #pragma unroll
    for (int t = 0; t < K / 32; ++t) {
        uint4 avn[4], bvn[4];
        if (t + 1 < K / 32) {
            #pragma unroll
            for (int rf = 0; rf < 4; ++rf)
                avn[rf] = *(const uint4*)(abase + rf * 16 * LDIN + (t + 1) * 64);
            #pragma unroll
            for (int cf = 0; cf < 4; ++cf)
                bvn[cf] = *(const uint4*)(wbase + ((((t + 1) * 256 + cf * 16) * 4) << 3));
        }
        __builtin_amdgcn_s_setprio(1);
        #pragma unroll
        for (int rf = 0; rf < 4; ++rf)
            #pragma unroll
            for (int cf = 0; cf < 4; ++cf)
                acc[rf][cf] = __builtin_amdgcn_mfma_f32_16x16x32_bf16(
                    __builtin_bit_cast(bf16x8, av[rf]),
                    __builtin_bit_cast(bf16x8, bv[cf]),
                    acc[rf][cf], 0, 0, 0);
        __builtin_amdgcn_s_setprio(0);
        if (t + 1 < K / 32) {
            #pragma unroll
            for (int i = 0; i < 4; ++i) { av[i] = avn[i]; bv[i] = bvn[i]; }
        }
    }
    if (INPLACE) __syncthreads();            // all reads of bin done before overwrite
    float bias[4];
    #pragma unroll
    for (int cf = 0; cf < 4; ++cf) bias[cf] = mb[n0 + 16 * cf + l15];
    unsigned char* sbase = bout + kg * 4 * ACTLD + (n0 + l15 * 4) * 2;
    #pragma unroll
    for (int rf = 0; rf < 4; ++rf) {
        f32x2 bA = mk2(bias[0], bias[0]), bB = mk2(bias[1], bias[1]);
        f32x2 bC = mk2(bias[2], bias[2]), bD = mk2(bias[3], bias[3]);
        f32x2 sA0 = silu2(__builtin_shufflevector(acc[rf][0], acc[rf][0], 0, 1) + bA);
        f32x2 sA1 = silu2(__builtin_shufflevector(acc[rf][0], acc[rf][0], 2, 3) + bA);
        f32x2 sB0 = silu2(__builtin_shufflevector(acc[rf][1], acc[rf][1], 0, 1) + bB);
        f32x2 sB1 = silu2(__builtin_shufflevector(acc[rf][1], acc[rf][1], 2, 3) + bB);
        f32x2 sC0 = silu2(__builtin_shufflevector(acc[rf][2], acc[rf][2], 0, 1) + bC);
        f32x2 sC1 = silu2(__builtin_shufflevector(acc[rf][2], acc[rf][2], 2, 3) + bC);
        f32x2 sD0 = silu2(__builtin_shufflevector(acc[rf][3], acc[rf][3], 0, 1) + bD);
        f32x2 sD1 = silu2(__builtin_shufflevector(acc[rf][3], acc[rf][3], 2, 3) + bD);
        uint2 pk;
        pk.x = cvt_pk_bf16(sA0[0], sB0[0]); pk.y = cvt_pk_bf16(sC0[0], sD0[0]);
        *(uint2*)(sbase + (rf * 16 + 0) * ACTLD) = pk;
        pk.x = cvt_pk_bf16(sA0[1], sB0[1]); pk.y = cvt_pk_bf16(sC0[1], sD0[1]);
        *(uint2*)(sbase + (rf * 16 + 1) * ACTLD) = pk;
        pk.x = cvt_pk_bf16(sA1[0], sB1[0]); pk.y = cvt_pk_bf16(sC1[0], sD1[0]);
        *(uint2*)(sbase + (rf * 16 + 2) * ACTLD) = pk;
        pk.x = cvt_pk_bf16(sA1[1], sB1[1]); pk.y = cvt_pk_bf16(sC1[1], sD1[1]);
        *(uint2*)(sbase + (rf * 16 + 3) * ACTLD) = pk;
    }
    __syncthreads();
}

__global__ __launch_bounds__(256) void k_mlp(
    const float* __restrict__ qp, const unsigned short* __restrict__ triT,
    const unsigned short* __restrict__ wt0, const unsigned short* __restrict__ wt1,
    const unsigned short* __restrict__ wt2,
    const float* __restrict__ mb0, const float* __restrict__ mb1, const float* __restrict__ mb2,
    const float* __restrict__ sdfp, const float* __restrict__ sdf_b,
    const float* __restrict__ occp, const float* __restrict__ occ_b,
    float* __restrict__ out)
{
    __shared__ __align__(16) unsigned char lds[64 * X0LD + 64 * ACTLD];  // 51200 B
    unsigned char* x0  = lds;                  // 64 rows x 272 B
    unsigned char* act = lds + 64 * X0LD;      // 64 rows x 528 B
    unsigned char* scr = act;                  // 192*32 B coord scratch (dead after phase B)
    const int t = threadIdx.x;

    // batch <-> XCD affinity (bijective: 4096 = 8 XCD * 512)
    const int bid = blockIdx.x;
    const int xcd = bid & 7;
    const int batch = xcd >> 1;
    const int brow = (bid >> 3) + ((xcd & 1) << 9);   // 0..1023
    const int row0 = batch * QPB + brow * 64;

    // ---- phase A: per (q,plane) corner BYTE offsets + weights -> scr ----
    if (t < 192) {
        int plane = t >> 6, q = t & 63;
        int gr = row0 + q;
        float px = qp[3 * gr], py = qp[3 * gr + 1], pz = qp[3 * gr + 2];
        float u = (plane == 2) ? py : px;
        float v = (plane == 0) ? py : pz;
        u = fminf(fmaxf(u, -1.f), 1.f);
        v = fminf(fmaxf(v, -1.f), 1.f);
        float xf = (u + 1.f) * 31.5f;
        float yf = (v + 1.f) * 31.5f;
        float x0f = floorf(xf), y0f = floorf(yf);
        float wx = xf - x0f, wy = yf - y0f;
        int xi = min(max((int)x0f, 0), 63);
        int yi = min(max((int)y0f, 0), 63);
        int xi1 = min(xi + 1, 63), yi1 = min(yi + 1, 63);
        int pb = (batch * 3 + plane) * 64;
        int4 offs;                             // byte offsets (64 B bf16 rows)
        offs.x = ((pb + yi ) * 64 + xi ) << 6;
        offs.y = ((pb + yi ) * 64 + xi1) << 6;
        offs.z = ((pb + yi1) * 64 + xi ) << 6;
        offs.w = ((pb + yi1) * 64 + xi1) << 6;
        float4 w;
        w.x = (1.f - wx) * (1.f - wy); w.y = wx * (1.f - wy);
        w.z = (1.f - wx) * wy;         w.w = wx * wy;
        *(int4*)(scr + t * 32) = offs;
        *(float4*)(scr + t * 32 + 16) = w;
        if (plane == 0) {
            uint4 c0;
            c0.x = (unsigned)f2bf(px) | ((unsigned)f2bf(py) << 16);
            c0.y = (unsigned)f2bf(pz);
            c0.z = 0u; c0.w = 0u;
            uint4 z4; z4.x = z4.y = z4.z = z4.w = 0u;
            *(uint4*)(x0 + q * X0LD + 192) = c0;
            *(uint4*)(x0 + q * X0LD + 208) = z4;
            *(uint4*)(x0 + q * X0LD + 224) = z4;
            *(uint4*)(x0 + q * X0LD + 240) = z4;
        }
    }
    __syncthreads();

    // ---- phase B: gather+blend from bf16 triT; 768 units = 192 x 4 chunks ----
    const char* tb8 = (const char*)triT;
    #pragma unroll
    for (int i = 0; i < 3; ++i) {
        int unit = i * 256 + t;
        int chunk = unit & 3;
        int uc = unit >> 2;                  // = plane*64 + q
        const unsigned char* ce = scr + uc * 32;
        int4 offs = *(const int4*)ce;
        float4 w = *(const float4*)(ce + 16);
        int cb = chunk * 16;
        uint4 c0 = *(const uint4*)(tb8 + offs.x + cb);
        uint4 c1 = *(const uint4*)(tb8 + offs.y + cb);
        uint4 c2 = *(const uint4*)(tb8 + offs.z + cb);
        uint4 c3 = *(const uint4*)(tb8 + offs.w + cb);
        const unsigned* u0 = (const unsigned*)&c0;
        const unsigned* u1 = (const unsigned*)&c1;
        const unsigned* u2 = (const unsigned*)&c2;
        const unsigned* u3 = (const unsigned*)&c3;
        f32x2 wx2 = mk2(w.x, w.x), wy2 = mk2(w.y, w.y);
        f32x2 wz2 = mk2(w.z, w.z), ww2 = mk2(w.w, w.w);
        unsigned r[4];
        #pragma unroll
        for (int q2 = 0; q2 < 4; ++q2) {
            f32x2 s = wx2 * lohi2(u0[q2]);
            s = fma2(wy2, lohi2(u1[q2]), s);
            s = fma2(wz2, lohi2(u2[q2]), s);
            s = fma2(ww2, lohi2(u3[q2]), s);
            r[q2] = cvt_pk_bf16(s[0], s[1]);
        }
        int q = uc & 63, plane = uc >> 6;
        uint4 pk; pk.x = r[0]; pk.y = r[1]; pk.z = r[2]; pk.w = r[3];
        *(uint4*)(x0 + q * X0LD + plane * 64 + chunk * 16) = pk;
    }
    __syncthreads();

    const int lane = t & 63;
    const int c4 = t >> 6;                   // col-wave 0..3

    mlp_layer<128, false, X0LD >(x0,  act, wt0, mb0, lane, c4);
    mlp_layer<256, true,  ACTLD>(act, act, wt1, mb1, lane, c4);
    mlp_layer<256, true,  ACTLD>(act, act, wt2, mb2, lane, c4);

    // ---- heads: sdf / occ (pk-FMA pairs; sigma-permuted cols + weights) ----
    {
        const int l15 = lane & 15;
        const int kg = lane >> 4;
        int row = c4 * 16 + l15;             // 0..63
        int gr = row0 + row;
        const unsigned char* hbase = act + row * ACTLD + kg * 128;
        f32x2 aS2 = mk2(0.f, 0.f), aO2 = mk2(0.f, 0.f);
        int kb = kg * 64;
        #pragma unroll
        for (int i = 0; i < 8; ++i) {
            int k = kb + i * 8;
            uint4 xv = *(const uint4*)(hbase + i * 16);
            const unsigned* xu = (const unsigned*)&xv;
            float4 s0 = *(const float4*)(sdfp + k);
            float4 s1 = *(const float4*)(sdfp + k + 4);
            float4 o0 = *(const float4*)(occp + k);
            float4 o1 = *(const float4*)(occp + k + 4);
            f32x2 xa = lohi2(xu[0]), xb = lohi2(xu[1]);
            f32x2 xc = lohi2(xu[2]), xd = lohi2(xu[3]);
            aS2 = fma2(xa, mk2(s0.x, s0.y), aS2);
            aS2 = fma2(xb, mk2(s0.z, s0.w), aS2);
            aS2 = fma2(xc, mk2(s1.x, s1.y), aS2);
            aS2 = fma2(xd, mk2(s1.z, s1.w), aS2);
            aO2 = fma2(xa, mk2(o0.x, o0.y), aO2);
            aO2 = fma2(xb, mk2(o0.z, o0.w), aO2);
            aO2 = fma2(xc, mk2(o1.x, o1.y), aO2);
            aO2 = fma2(xd, mk2(o1.z, o1.w), aO2);
        }
        float aS = aS2[0] + aS2[1];
        float aO = aO2[0] + aO2[1];
        aS += __shfl_xor(aS, 16);
        aS += __shfl_xor(aS, 32);
        aO += __shfl_xor(aO, 16);
        aO += __shfl_xor(aO, 32);
        if (kg == 0) {
            out[TRI_OUT + gr] = aS + sdf_b[0];
            out[TRI_OUT + QTOT + gr] = aO + occ_b[0];
        }
    }
}

extern "C" void kernel_launch(void* const* d_in, const int* in_sizes, int n_in,
                              void* d_out, int out_size, void* d_ws, size_t ws_size,
                              hipStream_t stream)
{
    const float* z     = (const float*)d_in[0];
    const float* qp    = (const float*)d_in[1];
    const float* w1    = (const float*)d_in[2];
    const float* b1    = (const float*)d_in[3];
    const float* w2    = (const float*)d_in[4];
    const float* b2    = (const float*)d_in[5];
    const float* mw0   = (const float*)d_in[6];
    const float* mb0   = (const float*)d_in[7];
    const float* mw1   = (const float*)d_in[8];
    const float* mb1   = (const float*)d_in[9];
    const float* mw2   = (const float*)d_in[10];
    const float* mb2   = (const float*)d_in[11];
    const float* sdf_w = (const float*)d_in[12];
    const float* sdf_b = (const float*)d_in[13];
    const float* occ_w = (const float*)d_in[14];
    const float* occ_b = (const float*)d_in[15];
    float* out = (float*)d_out;
    char* ws = (char*)d_ws;

    float* h_ws          = (float*)(ws);                    // 8192 B
    unsigned short* wt0  = (unsigned short*)(ws + 8192);    // 65536 B
    unsigned short* wt1  = (unsigned short*)(ws + 73728);   // 131072 B
    unsigned short* wt2  = (unsigned short*)(ws + 204800);  // 131072 B
    float* sdfp          = (float*)(ws + 335872);           // 1024 B
    float* occp          = (float*)(ws + 336896);           // 1024 B
    unsigned short* triT = (unsigned short*)(ws + 337920);  // 3145728 B (bf16)

    k_prep<<<650, 256, 0, stream>>>(mw0, mw1, mw2, sdf_w, occ_w, z, w1, b1,
                                    wt0, wt1, wt2, sdfp, occp, h_ws);
    k_triplane<<<768, 256, 0, stream>>>(w2, b2, h_ws, out, triT);
    k_mlp<<<4096, 256, 0, stream>>>(qp, triT, wt0, wt1, wt2,
                                    mb0, mb1, mb2, sdfp, sdf_b, occp, occ_b, out);
}